// Round 4
// baseline (231.437 us; speedup 1.0000x reference)
//
#include <hip/hip_runtime.h>
#include <hip/hip_fp16.h>

typedef _Float16 half2_t __attribute__((ext_vector_type(2)));
typedef _Float16 half4_t __attribute__((ext_vector_type(4)));
typedef _Float16 half8_t __attribute__((ext_vector_type(8)));
typedef float   float4_t __attribute__((ext_vector_type(4)));
typedef float  float16_t __attribute__((ext_vector_type(16)));

static __device__ __forceinline__ half2_t cvt_pk(float a, float b) {
    return __builtin_bit_cast(half2_t, __builtin_amdgcn_cvt_pkrtz(a, b));
}
static __device__ __forceinline__ half4_t cvt_pk4(float a, float b, float c, float d) {
    half2_t lo = cvt_pk(a, b), hi = cvt_pk(c, d);
    half4_t r;
    r[0] = lo[0]; r[1] = lo[1]; r[2] = hi[0]; r[3] = hi[1];
    return r;
}
static __device__ __forceinline__ half8_t cvt_pk8(const float4& a, const float4& b) {
    half4_t lo = cvt_pk4(a.x, a.y, a.z, a.w);
    half4_t hi = cvt_pk4(b.x, b.y, b.z, b.w);
    return __builtin_shufflevector(lo, hi, 0, 1, 2, 3, 4, 5, 6, 7);
}
static __device__ __forceinline__ half8_t join8(half4_t lo, half4_t hi) {
    return __builtin_shufflevector(lo, hi, 0, 1, 2, 3, 4, 5, 6, 7);
}
static __device__ __forceinline__ float f3(float a, float b, float c) {
    return fmaxf(fmaxf(a, b), c);   // clang fuses to v_max3_f32 (T17)
}

namespace {
constexpr int kB       = 16;    // batch
constexpr int kL       = 4096;  // Lq == Lk
constexpr int kD       = 64;    // head dim
constexpr int kQTile   = 128;   // 4 waves x 32 q-rows
constexpr int kBK      = 64;    // keys per tile
constexpr int kTiles   = kL / kBK;          // 64 key-tiles per batch
constexpr int kSplit   = 2;                 // K-split (grid 1024)
constexpr int kTilesHf = kTiles / kSplit;   // 32 key-tiles per half
constexpr int kTileH   = kBK * kD;          // 4096 halves per tile image
constexpr int kKStride = 72;    // Ksh stride (halves): b128 reads, even bank groups
constexpr size_t kWsHalves = (size_t)kB * kTiles * kTileH;  // 8 MB per operand
constexpr size_t kOHalves  = (size_t)kB * kL * kD;          // 8 MB fp16 partial O
}

// v15: V bypasses LDS (T14). R3 evidence: MFMA 32% / trueVALU ~17% / LDS 13%,
// tile-round 7.3k cyc vs ~2k max-pipe work -> dependency-stall bound. The V
// LDS round-trip (commit + ds_read, ~2x120cy in-chain) is pointless: the V
// image is PERFECTLY coalesced from global (1KB/instr) and L2-resident.
//  - V fragments: global->reg at iteration top (8x b128), consumed by PV
//    ~700cy later (QK+softmax cover). PV is now pure register MFMA.
//  - K stays LDS-shared (32B-granule global pattern, keep 4-way block reuse),
//    double-buffered, single barrier; commit moved after QK so the
//    post-barrier critical path starts at kf/QK immediately.
//  - LDS 36.9KB -> 18.4KB.
// Math identical to v13/v14: 32x32x16 QK/PV, key-bit-swap K image,
// defer-max THR=8, lane-local l with epilogue pair-combine.

__global__ __launch_bounds__(256) void prep_kv(const float* __restrict__ K,
                                               const float* __restrict__ V,
                                               _Float16* __restrict__ Kws,
                                               _Float16* __restrict__ Vws)
{
    int blk = blockIdx.x;
    const int tid = threadIdx.x;
    if (blk < kB * kTiles) {
        // K image: fp16 row-major per tile, with key bits 2<->3 swapped so the
        // 32x32 MFMA S-reg order matches the PV B-operand key order.
        const float* src = K + (size_t)blk * kTileH;
        _Float16* dst = Kws + (size_t)blk * kTileH;
#pragma unroll
        for (int i = 0; i < 2; ++i) {
            const int task = tid + 256 * i;
            const int row  = task >> 3;       // dst physical row 0..63
            const int g    = task & 7;
            const int srow = (row & ~12) | ((row & 4) << 1) | ((row & 8) >> 1);
            const float* p = src + srow * kD + g * 8;
            const float4 a  = *(const float4*)p;
            const float4 b2 = *(const float4*)(p + 4);
            *(half8_t*)(dst + task * 8) = cvt_pk8(a, b2);
        }
    } else {
        // V^T image: [c8 chunk][d][8 keys] halves; natural key order
        blk -= kB * kTiles;
        const float* src = V + (size_t)blk * kTileH;   // [key][d]
        _Float16* dst = Vws + (size_t)blk * kTileH;
        const int d  = tid & 63;
        const int vw = tid >> 6;
#pragma unroll
        for (int i = 0; i < 2; ++i) {
            const int c8 = vw * 2 + i;
            const int k0 = c8 * 8;
            float p[8];
#pragma unroll
            for (int j = 0; j < 8; ++j) p[j] = src[(k0 + j) * kD + d];
            half4_t lo = cvt_pk4(p[0], p[1], p[2], p[3]);
            half4_t hi = cvt_pk4(p[4], p[5], p[6], p[7]);
            *(half8_t*)(dst + (c8 * 64 + d) * 8) = join8(lo, hi);
        }
    }
}

__global__ __launch_bounds__(256, 4)
void fa_fwd(const float* __restrict__ Q, const _Float16* __restrict__ Kws,
            const _Float16* __restrict__ Vws, const float* __restrict__ scale_ptr,
            float* __restrict__ Out, _Float16* __restrict__ O2ws,
            float* __restrict__ Mlws)
{
    __shared__ __align__(16) _Float16 Ksh[2][kBK * kKStride];  // [buf][key_phys][d]

    const int tid  = threadIdx.x;
    const int wave = tid >> 6;
    const int lane = tid & 63;
    const int l31  = lane & 31;   // q-row (QK B / PV B col); key row (QK A); d row (PV A)
    const int hi   = lane >> 5;   // half-select: k = hi*8 + j

    const int b  = blockIdx.y;
    const int hf = blockIdx.z;    // key-split half
    const int q0 = blockIdx.x * kQTile + wave * 32;

    // K staging decomposition (matches image layout)
    const int task0 = tid, task1 = tid + 256;          // K: row=task>>3, g=task&7
    const int koff0 = (task0 >> 3) * kKStride + (task0 & 7) * 8;
    const int koff1 = (task1 >> 3) * kKStride + (task1 & 7) * 8;

    const float qscale = 1.4426950408889634f / scale_ptr[0];

    const float*    Qb = Q   + (size_t)b * kL * kD;
    const _Float16* Kt = Kws + ((size_t)b * kTiles + (size_t)hf * kTilesHf) * kTileH;
    const _Float16* Vt = Vws + ((size_t)b * kTiles + (size_t)hf * kTilesHf) * kTileH;

    // ---- Q fragments (B-operand 32x32x16: n=l31=qrow, k=hi*8+j, d=kd*16+k) ----
    half8_t qfrag[4];
    {
        const float* qrow = Qb + (size_t)(q0 + l31) * kD;
#pragma unroll
        for (int kd = 0; kd < 4; ++kd) {
            const float* p = qrow + kd * 16 + hi * 8;
            half8_t h;
#pragma unroll
            for (int j = 0; j < 8; ++j) h[j] = (_Float16)(p[j] * qscale);
            qfrag[kd] = h;
        }
    }

    // O^T accumulators: col=l31=q, row=d=(r&3)+8*(r>>2)+4*hi (+32*dt)
    float16_t O[2];
    O[0] = (float16_t)0.0f;
    O[1] = (float16_t)0.0f;
    float m_run = -__builtin_inff();
    float l_run = 0.0f;   // lane-local (this half's keys); pair-combined in epilogue
    const float16_t Zc = (float16_t)0.0f;

    // ---- prologue: stage K tile 0 into buf0, prefetch K tile 1 into regs ----
    half8_t kp[2];
    kp[0] = *(const half8_t*)(Kt + task0 * 8);
    kp[1] = *(const half8_t*)(Kt + task1 * 8);
    *(half8_t*)(&Ksh[0][koff0]) = kp[0];
    *(half8_t*)(&Ksh[0][koff1]) = kp[1];
    kp[0] = *(const half8_t*)(Kt + (size_t)kTileH + task0 * 8);
    kp[1] = *(const half8_t*)(Kt + (size_t)kTileH + task1 * 8);
    __syncthreads();

    for (int t = 0; t < kTilesHf; ++t) {
        const int cur = t & 1;
        const _Float16* Kb = Ksh[cur];
        _Float16* Kn = Ksh[cur ^ 1];

        // ---- V(t) direct global->reg (8x b128, perfectly coalesced; consumed
        //      by PV ~700cy later -> latency fully covered) ----
        const _Float16* vtile = Vt + (size_t)t * kTileH;
        half8_t vr0[4], vr1[4];
#pragma unroll
        for (int kb = 0; kb < 4; ++kb) {
            const _Float16* pch = vtile + (kb * 2 + hi) * 512;
            vr0[kb] = *(const half8_t*)(pch + l31 * 8);
            vr1[kb] = *(const half8_t*)(pch + (32 + l31) * 8);
        }

        // ---- S^T = K_phys * Q^T : 2 key-blocks x 4 d-chunks of 32x32x16 ----
        float16_t S0, S1;
        {
            half8_t kf0, kf1;
            kf0 = *(const half8_t*)(&Kb[(l31)      * kKStride + 0 * 16 + hi * 8]);
            kf1 = *(const half8_t*)(&Kb[(32 + l31) * kKStride + 0 * 16 + hi * 8]);
            __builtin_amdgcn_s_setprio(1);
            S0 = __builtin_amdgcn_mfma_f32_32x32x16_f16(kf0, qfrag[0], Zc, 0, 0, 0);
            S1 = __builtin_amdgcn_mfma_f32_32x32x16_f16(kf1, qfrag[0], Zc, 0, 0, 0);
#pragma unroll
            for (int kd = 1; kd < 4; ++kd) {
                kf0 = *(const half8_t*)(&Kb[(l31)      * kKStride + kd * 16 + hi * 8]);
                kf1 = *(const half8_t*)(&Kb[(32 + l31) * kKStride + kd * 16 + hi * 8]);
                S0 = __builtin_amdgcn_mfma_f32_32x32x16_f16(kf0, qfrag[kd], S0, 0, 0, 0);
                S1 = __builtin_amdgcn_mfma_f32_32x32x16_f16(kf1, qfrag[kd], S1, 0, 0, 0);
            }
            __builtin_amdgcn_s_setprio(0);
        }

        // ---- commit K(t+1) into other buffer (its readers synced at t-1 end);
        //      prefetch K(t+2) into regs (wraps; wrapped data unused) ----
        *(half8_t*)(&Kn[koff0]) = kp[0];
        *(half8_t*)(&Kn[koff1]) = kp[1];
        {
            const int nt = (t + 2) & (kTilesHf - 1);
            const _Float16* kn = Kt + (size_t)nt * kTileH;
            kp[0] = *(const half8_t*)(kn + task0 * 8);
            kp[1] = *(const half8_t*)(kn + task1 * 8);
        }

        // ---- online softmax: max3 tree, ONE shfl_xor(32), lane-local l ----
        float v0 = f3(S0[0],  S0[1],  S0[2]);
        float v1 = f3(S0[3],  S0[4],  S0[5]);
        float v2 = f3(S0[6],  S0[7],  S0[8]);
        float v3 = f3(S0[9],  S0[10], S0[11]);
        float v4 = f3(S0[12], S0[13], S0[14]);
        float v5 = f3(S0[15], S1[0],  S1[1]);
        float v6 = f3(S1[2],  S1[3],  S1[4]);
        float v7 = f3(S1[5],  S1[6],  S1[7]);
        float v8 = f3(S1[8],  S1[9],  S1[10]);
        float v9 = f3(S1[11], S1[12], S1[13]);
        float w0 = f3(v0, v1, v2);
        float w1 = f3(v3, v4, v5);
        float w2 = f3(v6, v7, v8);
        float w3 = f3(v9, S1[14], S1[15]);
        float pm = fmaxf(fmaxf(w0, w1), fmaxf(w2, w3));
        pm = fmaxf(pm, __shfl_xor(pm, 32));

        // T13 defer-max: skip rescale while growth <= 8 (P bounded by 2^8, exact)
        const bool need = pm > m_run + 8.0f;
        if (__ballot(need)) {
            const float mn    = fmaxf(m_run, pm);
            const float alpha = __builtin_amdgcn_exp2f(m_run - mn);  // 1st iter: 0
            m_run = mn;
            l_run *= alpha;
#pragma unroll
            for (int r = 0; r < 16; ++r) { O[0][r] *= alpha; O[1][r] *= alpha; }
        }

        // ---- P = exp2(S - m) in place; pack B-fragments; local l sum ----
#pragma unroll
        for (int r = 0; r < 16; ++r) {
            S0[r] = __builtin_amdgcn_exp2f(S0[r] - m_run);
            S1[r] = __builtin_amdgcn_exp2f(S1[r] - m_run);
        }
        half8_t pf[4];
        pf[0] = join8(cvt_pk4(S0[0],  S0[1],  S0[2],  S0[3]),
                      cvt_pk4(S0[4],  S0[5],  S0[6],  S0[7]));
        pf[1] = join8(cvt_pk4(S0[8],  S0[9],  S0[10], S0[11]),
                      cvt_pk4(S0[12], S0[13], S0[14], S0[15]));
        pf[2] = join8(cvt_pk4(S1[0],  S1[1],  S1[2],  S1[3]),
                      cvt_pk4(S1[4],  S1[5],  S1[6],  S1[7]));
        pf[3] = join8(cvt_pk4(S1[8],  S1[9],  S1[10], S1[11]),
                      cvt_pk4(S1[12], S1[13], S1[14], S1[15]));
#define A4(v,a) ((v[a] + v[(a)+1]) + (v[(a)+2] + v[(a)+3]))
        l_run += ((A4(S0, 0) + A4(S0, 4)) + (A4(S0, 8) + A4(S0, 12)))
               + ((A4(S1, 0) + A4(S1, 4)) + (A4(S1, 8) + A4(S1, 12)));
#undef A4

        // ---- O^T += V^T * P : pure register MFMA (V already in vr0/vr1) ----
        __builtin_amdgcn_s_setprio(1);
#pragma unroll
        for (int kb = 0; kb < 4; ++kb) {
            O[0] = __builtin_amdgcn_mfma_f32_32x32x16_f16(vr0[kb], pf[kb], O[0], 0, 0, 0);
            O[1] = __builtin_amdgcn_mfma_f32_32x32x16_f16(vr1[kb], pf[kb], O[1], 0, 0, 0);
        }
        __builtin_amdgcn_s_setprio(0);

        // single barrier per tile: QK reads of buf[cur] done; commit to buf[cur^1] done
        __syncthreads();
    }

    // ---- epilogue: combine lane-pair l; O^T reg r -> d=(r&3)+8*(r>>2)+4*hi+32*dt ----
    l_run += __shfl_xor(l_run, 32);
    const float inv = 1.0f / l_run;
    const int   q   = q0 + l31;
    if (hf == 0) {
        float* op = Out + ((size_t)b * kL + q) * kD;
#pragma unroll
        for (int dt = 0; dt < 2; ++dt)
#pragma unroll
            for (int rr = 0; rr < 4; ++rr) {
                const int d0 = dt * 32 + rr * 8 + hi * 4;
                float4 w;
                w.x = O[dt][rr * 4 + 0] * inv;
                w.y = O[dt][rr * 4 + 1] * inv;
                w.z = O[dt][rr * 4 + 2] * inv;
                w.w = O[dt][rr * 4 + 3] * inv;
                *(float4*)(op + d0) = w;
            }
    } else {
        _Float16* op = O2ws + ((size_t)b * kL + q) * kD;
#pragma unroll
        for (int dt = 0; dt < 2; ++dt)
#pragma unroll
            for (int rr = 0; rr < 4; ++rr) {
                const int d0 = dt * 32 + rr * 8 + hi * 4;
                half4_t w = cvt_pk4(O[dt][rr * 4 + 0] * inv, O[dt][rr * 4 + 1] * inv,
                                    O[dt][rr * 4 + 2] * inv, O[dt][rr * 4 + 3] * inv);
                *(half4_t*)(op + d0) = w;
            }
    }
    if (hi == 0) {
        float2 ml; ml.x = m_run; ml.y = l_run;
        *(float2*)(Mlws + (((size_t)b * kL + q) * 2 + hf) * 2) = ml;
    }
}

// Merge the two key-halves: Out = w1*O1 + w2*O2, w_i = l_i*2^(m_i-m) / sum.
__global__ __launch_bounds__(256)
void combine(float* __restrict__ Out, const _Float16* __restrict__ O2ws,
             const float* __restrict__ Mlws)
{
    const int t   = threadIdx.x;
    const int row = blockIdx.x * 16 + (t >> 4);   // global row in [0, kB*kL)
    const int d0  = (t & 15) * 4;

    const float m1 = Mlws[(size_t)row * 4 + 0];
    const float l1 = Mlws[(size_t)row * 4 + 1];
    const float m2 = Mlws[(size_t)row * 4 + 2];
    const float l2 = Mlws[(size_t)row * 4 + 3];

    const float m  = fmaxf(m1, m2);
    float w1 = l1 * exp2f(m1 - m);
    float w2 = l2 * exp2f(m2 - m);
    const float inv = 1.0f / (w1 + w2);
    w1 *= inv; w2 *= inv;

    float* op = Out + (size_t)row * kD + d0;
    const _Float16* o2 = O2ws + (size_t)row * kD + d0;
    float4 a = *(const float4*)op;
    const half4_t h = *(const half4_t*)o2;
    a.x = a.x * w1 + (float)h[0] * w2;
    a.y = a.y * w1 + (float)h[1] * w2;
    a.z = a.z * w1 + (float)h[2] * w2;
    a.w = a.w * w1 + (float)h[3] * w2;
    *(float4*)op = a;
}

extern "C" void kernel_launch(void* const* d_in, const int* in_sizes, int n_in,
                              void* d_out, int out_size, void* d_ws, size_t ws_size,
                              hipStream_t stream) {
    const float* Q = (const float*)d_in[0];
    const float* K = (const float*)d_in[1];
    const float* V = (const float*)d_in[2];
    const float* s = (const float*)d_in[3];
    float* out = (float*)d_out;
    _Float16* Kws  = (_Float16*)d_ws;
    _Float16* Vws  = Kws + kWsHalves;
    _Float16* O2ws = Vws + kWsHalves;                 // 8.4 MB fp16 partial (half 1)
    float*    Mlws = (float*)(O2ws + kOHalves);       // [b*L][half][{m,l}] = 1.05 MB
    // total ws use: 16.8 + 8.4 + 1.05 = 26.2 MB  (>=34 MB proven in R5)

    prep_kv<<<dim3(2 * kB * kTiles), dim3(256), 0, stream>>>(K, V, Kws, Vws);
    fa_fwd<<<dim3(kL / kQTile, kB, kSplit), dim3(256), 0, stream>>>(Q, Kws, Vws, s, out, O2ws, Mlws);
    combine<<<dim3(kB * kL / 16), dim3(256), 0, stream>>>(out, O2ws, Mlws);
}

// Round 5
// 197.623 us; speedup vs baseline: 1.1711x; 1.1711x over previous
//
#include <hip/hip_runtime.h>
#include <hip/hip_fp16.h>

typedef _Float16 half2_t __attribute__((ext_vector_type(2)));
typedef _Float16 half4_t __attribute__((ext_vector_type(4)));
typedef _Float16 half8_t __attribute__((ext_vector_type(8)));
typedef float   float4_t __attribute__((ext_vector_type(4)));
typedef float  float16_t __attribute__((ext_vector_type(16)));

static __device__ __forceinline__ half2_t cvt_pk(float a, float b) {
    return __builtin_bit_cast(half2_t, __builtin_amdgcn_cvt_pkrtz(a, b));
}
static __device__ __forceinline__ half4_t cvt_pk4(float a, float b, float c, float d) {
    half2_t lo = cvt_pk(a, b), hi = cvt_pk(c, d);
    half4_t r;
    r[0] = lo[0]; r[1] = lo[1]; r[2] = hi[0]; r[3] = hi[1];
    return r;
}
static __device__ __forceinline__ half8_t cvt_pk8(const float4& a, const float4& b) {
    half4_t lo = cvt_pk4(a.x, a.y, a.z, a.w);
    half4_t hi = cvt_pk4(b.x, b.y, b.z, b.w);
    return __builtin_shufflevector(lo, hi, 0, 1, 2, 3, 4, 5, 6, 7);
}
static __device__ __forceinline__ half8_t join8(half4_t lo, half4_t hi) {
    return __builtin_shufflevector(lo, hi, 0, 1, 2, 3, 4, 5, 6, 7);
}
static __device__ __forceinline__ float f3(float a, float b, float c) {
    return fmaxf(fmaxf(a, b), c);   // clang fuses to v_max3_f32 (T17)
}

// HBM -> LDS direct (16B per lane). LDS dest must be wave-uniform base;
// HW writes base + lane*16 (m03/m97/m104). Permutations live in the image.
static __device__ __forceinline__ void stage16(const _Float16* g, _Float16* l) {
    __builtin_amdgcn_global_load_lds(
        (const __attribute__((address_space(1))) char*)(const void*)g,
        (__attribute__((address_space(3))) char*)(void*)l, 16, 0, 0);
}

namespace {
constexpr int kB       = 16;    // batch
constexpr int kL       = 4096;  // Lq == Lk
constexpr int kD       = 64;    // head dim
constexpr int kQTile   = 128;   // 4 waves x 32 q-rows
constexpr int kBK      = 64;    // keys per tile
constexpr int kTiles   = kL / kBK;          // 64 key-tiles per batch
constexpr int kSplit   = 2;                 // K-split (grid 1024)
constexpr int kTilesHf = kTiles / kSplit;   // 32 key-tiles per half
constexpr int kTileH   = kBK * kD;          // 4096 halves per tile image
constexpr int kBufH    = 2 * kTileH;        // K tile + V tile halves per buffer
constexpr size_t kWsHalves = (size_t)kB * kTiles * kTileH;  // 8 MB per operand
constexpr size_t kOHalves  = (size_t)kB * kL * kD;          // 8 MB fp16 partial O
}

// v16: staging via global_load_lds, zero staging VGPRs. R4 post-mortem: v15's
// V-in-reg spilled (WRITE_SIZE 33->163MB = scratch) -> revert to v14 base.
// v14's residual spine: vmcnt wait -> 6 ds_writes -> barrier + 24 VGPRs of
// kp/vp/koff/voff. Replace with 4x global_load_lds (width 16) per thread per
// tile, double-buffered, single barrier (implicit vmcnt(0) drains prefetch
// that had a full tile of slack, L2-resident).
//  - LDS linear (gl_lds requirement, m104/m173): K image carries the XOR
//    swizzle in content (chunk g -> g^(row&7) within each 128B row; prep
//    stays fully coalesced); ds_read applies the same involution. V image
//    [c8][d][8keys] is already copy-compatible + contiguous-lane reads.
//  - all per-tile LDS read addrs = 5 precomputed per-lane VGPRs + imm.
//  - LDS 36.9 -> 32 KB.
// Math identical to v13/v14: 32x32x16 QK/PV, key-bit-swap K image,
// defer-max THR=8, lane-local l with epilogue pair-combine.

__global__ __launch_bounds__(256) void prep_kv(const float* __restrict__ K,
                                               const float* __restrict__ V,
                                               _Float16* __restrict__ Kws,
                                               _Float16* __restrict__ Vws)
{
    int blk = blockIdx.x;
    const int tid = threadIdx.x;
    if (blk < kB * kTiles) {
        // K image: fp16 per tile; rows bit2<->bit3 swapped (S-reg -> PV key
        // order, proven v13); within each row the 16B chunk index is XORed
        // with (row&7) so the LINEAR-copied LDS tile is bank-conflict-free
        // under the kf read pattern. Reads & writes both stay coalesced.
        const float* src = K + (size_t)blk * kTileH;
        _Float16* dst = Kws + (size_t)blk * kTileH;
#pragma unroll
        for (int i = 0; i < 2; ++i) {
            const int task = tid + 256 * i;
            const int row  = task >> 3;       // dst physical row 0..63
            const int gp   = task & 7;        // dst physical 16B chunk
            const int srow = (row & ~12) | ((row & 4) << 1) | ((row & 8) >> 1);
            const int glog = gp ^ (row & 7);  // logical d-chunk stored here
            const float* p = src + srow * kD + glog * 8;
            const float4 a  = *(const float4*)p;
            const float4 b2 = *(const float4*)(p + 4);
            *(half8_t*)(dst + task * 8) = cvt_pk8(a, b2);
        }
    } else {
        // V^T image: [c8 chunk][d][8 keys] halves == the LDS layout verbatim
        blk -= kB * kTiles;
        const float* src = V + (size_t)blk * kTileH;   // [key][d]
        _Float16* dst = Vws + (size_t)blk * kTileH;
        const int d  = tid & 63;
        const int vw = tid >> 6;
#pragma unroll
        for (int i = 0; i < 2; ++i) {
            const int c8 = vw * 2 + i;
            const int k0 = c8 * 8;
            float p[8];
#pragma unroll
            for (int j = 0; j < 8; ++j) p[j] = src[(k0 + j) * kD + d];
            half4_t lo = cvt_pk4(p[0], p[1], p[2], p[3]);
            half4_t hi = cvt_pk4(p[4], p[5], p[6], p[7]);
            *(half8_t*)(dst + (c8 * 64 + d) * 8) = join8(lo, hi);
        }
    }
}

__global__ __launch_bounds__(256, 4)
void fa_fwd(const float* __restrict__ Q, const _Float16* __restrict__ Kws,
            const _Float16* __restrict__ Vws, const float* __restrict__ scale_ptr,
            float* __restrict__ Out, _Float16* __restrict__ O2ws,
            float* __restrict__ Mlws)
{
    // [buf][ K tile 4096 halves | V tile 4096 halves ] -- strictly linear
    __shared__ __align__(16) _Float16 SH[2 * kBufH];   // 32 KB

    const int tid  = threadIdx.x;
    const int wave = tid >> 6;
    const int lane = tid & 63;
    const int l31  = lane & 31;   // q-row (QK B / PV B col); key row (QK A); d row (PV A)
    const int hi   = lane >> 5;   // half-select: k = hi*8 + j

    const int b  = blockIdx.y;
    const int hf = blockIdx.z;    // key-split half
    const int q0 = blockIdx.x * kQTile + wave * 32;

    const float qscale = 1.4426950408889634f / scale_ptr[0];

    const float*    Qb = Q   + (size_t)b * kL * kD;
    const _Float16* Kt = Kws + ((size_t)b * kTiles + (size_t)hf * kTilesHf) * kTileH;
    const _Float16* Vt = Vws + ((size_t)b * kTiles + (size_t)hf * kTilesHf) * kTileH;

    // ---- precomputed per-lane LDS read half-indices (buf/kb/kd via imm) ----
    const int rs = l31 & 7;
    int ka[4];
#pragma unroll
    for (int kd = 0; kd < 4; ++kd)
        ka[kd] = l31 * 64 + (((kd * 2 + hi) ^ rs) << 3);  // K: row l31, chunk kd*2+hi
    const int va = kTileH + hi * 512 + l31 * 8;           // V: c8=kb*2+hi, d=l31

    // staging: thread tid's 16B lands at LDS halves [wave*512 + lane*8] ----
    const int sdst = wave * 512;   // + lane*8 applied by HW

    // ---- Q fragments (B-operand 32x32x16: n=l31=qrow, k=hi*8+j, d=kd*16+k) ----
    half8_t qfrag[4];
    {
        const float* qrow = Qb + (size_t)(q0 + l31) * kD;
#pragma unroll
        for (int kd = 0; kd < 4; ++kd) {
            const float* p = qrow + kd * 16 + hi * 8;
            half8_t h;
#pragma unroll
            for (int j = 0; j < 8; ++j) h[j] = (_Float16)(p[j] * qscale);
            qfrag[kd] = h;
        }
    }

    // O^T accumulators: col=l31=q, row=d=(r&3)+8*(r>>2)+4*hi (+32*dt)
    float16_t O[2];
    O[0] = (float16_t)0.0f;
    O[1] = (float16_t)0.0f;
    float m_run = -__builtin_inff();
    float l_run = 0.0f;   // lane-local (this half's keys); pair-combined in epilogue
    const float16_t Zc = (float16_t)0.0f;

    // ---- prologue: stage tile 0 into buf0 ----
    stage16(Kt + tid * 8,                SH + sdst);
    stage16(Kt + (tid + 256) * 8,        SH + 2048 + sdst);
    stage16(Vt + tid * 8,                SH + kTileH + sdst);
    stage16(Vt + (tid + 256) * 8,        SH + kTileH + 2048 + sdst);
    __syncthreads();   // implicit vmcnt(0): tile 0 resident

    for (int t = 0; t < kTilesHf; ++t) {
        const int cb = (t & 1) * kBufH;         // current buffer base (halves)
        const int nb = ((t + 1) & 1) * kBufH;   // next buffer base

        // ---- stage tile t+1 into other buffer (DMA, zero VGPR; drained by
        //      this iteration's end barrier) ----
        {
            const int nt = (t + 1) & (kTilesHf - 1);
            const _Float16* kg = Kt + (size_t)nt * kTileH;
            const _Float16* vg = Vt + (size_t)nt * kTileH;
            stage16(kg + tid * 8,         SH + nb + sdst);
            stage16(kg + (tid + 256) * 8, SH + nb + 2048 + sdst);
            stage16(vg + tid * 8,         SH + nb + kTileH + sdst);
            stage16(vg + (tid + 256) * 8, SH + nb + kTileH + 2048 + sdst);
        }

        // ---- S^T = K_phys * Q^T : 2 key-blocks x 4 d-chunks of 32x32x16 ----
        float16_t S0, S1;
        {
            half8_t kf0, kf1;
            kf0 = *(const half8_t*)(&SH[cb + ka[0]]);
            kf1 = *(const half8_t*)(&SH[cb + ka[0] + 2048]);
            __builtin_amdgcn_s_setprio(1);
            S0 = __builtin_amdgcn_mfma_f32_32x32x16_f16(kf0, qfrag[0], Zc, 0, 0, 0);
            S1 = __builtin_amdgcn_mfma_f32_32x32x16_f16(kf1, qfrag[0], Zc, 0, 0, 0);
#pragma unroll
            for (int kd = 1; kd < 4; ++kd) {
                kf0 = *(const half8_t*)(&SH[cb + ka[kd]]);
                kf1 = *(const half8_t*)(&SH[cb + ka[kd] + 2048]);
                S0 = __builtin_amdgcn_mfma_f32_32x32x16_f16(kf0, qfrag[kd], S0, 0, 0, 0);
                S1 = __builtin_amdgcn_mfma_f32_32x32x16_f16(kf1, qfrag[kd], S1, 0, 0, 0);
            }
            __builtin_amdgcn_s_setprio(0);
        }

        // ---- vf reads issued early: LDS latency overlaps the softmax ----
        half8_t vf0[4], vf1[4];
#pragma unroll
        for (int kb = 0; kb < 4; ++kb) {
            vf0[kb] = *(const half8_t*)(&SH[cb + va + kb * 1024]);
            vf1[kb] = *(const half8_t*)(&SH[cb + va + kb * 1024 + 256]);
        }

        // ---- online softmax: max3 tree, ONE shfl_xor(32), lane-local l ----
        float v0 = f3(S0[0],  S0[1],  S0[2]);
        float v1 = f3(S0[3],  S0[4],  S0[5]);
        float v2 = f3(S0[6],  S0[7],  S0[8]);
        float v3 = f3(S0[9],  S0[10], S0[11]);
        float v4 = f3(S0[12], S0[13], S0[14]);
        float v5 = f3(S0[15], S1[0],  S1[1]);
        float v6 = f3(S1[2],  S1[3],  S1[4]);
        float v7 = f3(S1[5],  S1[6],  S1[7]);
        float v8 = f3(S1[8],  S1[9],  S1[10]);
        float v9 = f3(S1[11], S1[12], S1[13]);
        float w0 = f3(v0, v1, v2);
        float w1 = f3(v3, v4, v5);
        float w2 = f3(v6, v7, v8);
        float w3 = f3(v9, S1[14], S1[15]);
        float pm = fmaxf(fmaxf(w0, w1), fmaxf(w2, w3));
        pm = fmaxf(pm, __shfl_xor(pm, 32));

        // T13 defer-max: skip rescale while growth <= 8 (P bounded by 2^8, exact)
        const bool need = pm > m_run + 8.0f;
        if (__ballot(need)) {
            const float mn    = fmaxf(m_run, pm);
            const float alpha = __builtin_amdgcn_exp2f(m_run - mn);  // 1st iter: 0
            m_run = mn;
            l_run *= alpha;
#pragma unroll
            for (int r = 0; r < 16; ++r) { O[0][r] *= alpha; O[1][r] *= alpha; }
        }

        // ---- P = exp2(S - m) in place; pack B-fragments; local l sum ----
#pragma unroll
        for (int r = 0; r < 16; ++r) {
            S0[r] = __builtin_amdgcn_exp2f(S0[r] - m_run);
            S1[r] = __builtin_amdgcn_exp2f(S1[r] - m_run);
        }
        half8_t pf[4];
        pf[0] = join8(cvt_pk4(S0[0],  S0[1],  S0[2],  S0[3]),
                      cvt_pk4(S0[4],  S0[5],  S0[6],  S0[7]));
        pf[1] = join8(cvt_pk4(S0[8],  S0[9],  S0[10], S0[11]),
                      cvt_pk4(S0[12], S0[13], S0[14], S0[15]));
        pf[2] = join8(cvt_pk4(S1[0],  S1[1],  S1[2],  S1[3]),
                      cvt_pk4(S1[4],  S1[5],  S1[6],  S1[7]));
        pf[3] = join8(cvt_pk4(S1[8],  S1[9],  S1[10], S1[11]),
                      cvt_pk4(S1[12], S1[13], S1[14], S1[15]));
#define A4(v,a) ((v[a] + v[(a)+1]) + (v[(a)+2] + v[(a)+3]))
        l_run += ((A4(S0, 0) + A4(S0, 4)) + (A4(S0, 8) + A4(S0, 12)))
               + ((A4(S1, 0) + A4(S1, 4)) + (A4(S1, 8) + A4(S1, 12)));
#undef A4

        // ---- O^T += V^T * P : 4 key16-blocks x 2 d-blocks, full-rate x32x16 ----
        __builtin_amdgcn_s_setprio(1);
#pragma unroll
        for (int kb = 0; kb < 4; ++kb) {
            O[0] = __builtin_amdgcn_mfma_f32_32x32x16_f16(vf0[kb], pf[kb], O[0], 0, 0, 0);
            O[1] = __builtin_amdgcn_mfma_f32_32x32x16_f16(vf1[kb], pf[kb], O[1], 0, 0, 0);
        }
        __builtin_amdgcn_s_setprio(0);

        // single barrier: reads of buf[cur] done; DMA into buf[nxt] drained
        __syncthreads();
    }

    // ---- epilogue: combine lane-pair l; O^T reg r -> d=(r&3)+8*(r>>2)+4*hi+32*dt ----
    l_run += __shfl_xor(l_run, 32);
    const float inv = 1.0f / l_run;
    const int   q   = q0 + l31;
    if (hf == 0) {
        float* op = Out + ((size_t)b * kL + q) * kD;
#pragma unroll
        for (int dt = 0; dt < 2; ++dt)
#pragma unroll
            for (int rr = 0; rr < 4; ++rr) {
                const int d0 = dt * 32 + rr * 8 + hi * 4;
                float4 w;
                w.x = O[dt][rr * 4 + 0] * inv;
                w.y = O[dt][rr * 4 + 1] * inv;
                w.z = O[dt][rr * 4 + 2] * inv;
                w.w = O[dt][rr * 4 + 3] * inv;
                *(float4*)(op + d0) = w;
            }
    } else {
        _Float16* op = O2ws + ((size_t)b * kL + q) * kD;
#pragma unroll
        for (int dt = 0; dt < 2; ++dt)
#pragma unroll
            for (int rr = 0; rr < 4; ++rr) {
                const int d0 = dt * 32 + rr * 8 + hi * 4;
                half4_t w = cvt_pk4(O[dt][rr * 4 + 0] * inv, O[dt][rr * 4 + 1] * inv,
                                    O[dt][rr * 4 + 2] * inv, O[dt][rr * 4 + 3] * inv);
                *(half4_t*)(op + d0) = w;
            }
    }
    if (hi == 0) {
        float2 ml; ml.x = m_run; ml.y = l_run;
        *(float2*)(Mlws + (((size_t)b * kL + q) * 2 + hf) * 2) = ml;
    }
}

// Merge the two key-halves: Out = w1*O1 + w2*O2, w_i = l_i*2^(m_i-m) / sum.
__global__ __launch_bounds__(256)
void combine(float* __restrict__ Out, const _Float16* __restrict__ O2ws,
             const float* __restrict__ Mlws)
{
    const int t   = threadIdx.x;
    const int row = blockIdx.x * 16 + (t >> 4);   // global row in [0, kB*kL)
    const int d0  = (t & 15) * 4;

    const float m1 = Mlws[(size_t)row * 4 + 0];
    const float l1 = Mlws[(size_t)row * 4 + 1];
    const float m2 = Mlws[(size_t)row * 4 + 2];
    const float l2 = Mlws[(size_t)row * 4 + 3];

    const float m  = fmaxf(m1, m2);
    float w1 = l1 * exp2f(m1 - m);
    float w2 = l2 * exp2f(m2 - m);
    const float inv = 1.0f / (w1 + w2);
    w1 *= inv; w2 *= inv;

    float* op = Out + (size_t)row * kD + d0;
    const _Float16* o2 = O2ws + (size_t)row * kD + d0;
    float4 a = *(const float4*)op;
    const half4_t h = *(const half4_t*)o2;
    a.x = a.x * w1 + (float)h[0] * w2;
    a.y = a.y * w1 + (float)h[1] * w2;
    a.z = a.z * w1 + (float)h[2] * w2;
    a.w = a.w * w1 + (float)h[3] * w2;
    *(float4*)op = a;
}

extern "C" void kernel_launch(void* const* d_in, const int* in_sizes, int n_in,
                              void* d_out, int out_size, void* d_ws, size_t ws_size,
                              hipStream_t stream) {
    const float* Q = (const float*)d_in[0];
    const float* K = (const float*)d_in[1];
    const float* V = (const float*)d_in[2];
    const float* s = (const float*)d_in[3];
    float* out = (float*)d_out;
    _Float16* Kws  = (_Float16*)d_ws;
    _Float16* Vws  = Kws + kWsHalves;
    _Float16* O2ws = Vws + kWsHalves;                 // 8.4 MB fp16 partial (half 1)
    float*    Mlws = (float*)(O2ws + kOHalves);       // [b*L][half][{m,l}] = 1.05 MB
    // total ws use: 16.8 + 8.4 + 1.05 = 26.2 MB  (>=34 MB proven in R5)

    prep_kv<<<dim3(2 * kB * kTiles), dim3(256), 0, stream>>>(K, V, Kws, Vws);
    fa_fwd<<<dim3(kL / kQTile, kB, kSplit), dim3(256), 0, stream>>>(Q, Kws, Vws, s, out, O2ws, Mlws);
    combine<<<dim3(kB * kL / 16), dim3(256), 0, stream>>>(out, O2ws, Mlws);
}